// Round 1
// baseline (781.494 us; speedup 1.0000x reference)
//
#include <hip/hip_runtime.h>

// Problem constants (B = 262144 rows, features 256 -> 64 -> 16 -> 4).
#define NB1 512   // blocks for main kernel: 2 resident per CU (LDS-limited)
#define TPB 256   // 4 waves per block

// LDS layout (floats), total 20244 floats = 80976 bytes (dynamic LDS).
#define OFF_W2 16384
#define OFF_W3 17408
#define OFF_B1 17472
#define OFF_B2 17536
#define OFF_B3 17552
#define OFF_H1 17556              // [4 waves][8 rows][68 padded]
#define H1_STRIDE 68
#define OFF_H2 (OFF_H1 + 4*8*H1_STRIDE)   // [4 waves][8 rows][16]
#define SMEM_FLOATS (OFF_H2 + 4*8*16)
#define SMEM_BYTES (SMEM_FLOATS * 4)

extern __shared__ float smem[];

__global__ __launch_bounds__(TPB, 2) void fused_mlp_kernel(
    const float* __restrict__ x,
    const float* __restrict__ wz1, const float* __restrict__ b1,
    const float* __restrict__ wz2, const float* __restrict__ b2,
    const float* __restrict__ wz3, const float* __restrict__ b3,
    float* __restrict__ Eout, float* __restrict__ block_sums,
    int groups_per_wave)
{
    float* sw1 = smem;             // [256][64]
    float* sw2 = smem + OFF_W2;    // [64][16]
    float* sw3 = smem + OFF_W3;    // [16][4]
    float* sb1 = smem + OFF_B1;    // [64]
    float* sb2 = smem + OFF_B2;    // [16]
    float* sb3 = smem + OFF_B3;    // [4]
    float* sh1 = smem + OFF_H1;
    float* sh2 = smem + OFF_H2;

    const int tid = threadIdx.x;

    // ---- stage weights/biases into LDS (coalesced float4) ----
    {
        const float4* s1 = (const float4*)wz1;
        float4* d1 = (float4*)sw1;
        #pragma unroll
        for (int i = 0; i < 16; ++i) d1[tid + i * TPB] = s1[tid + i * TPB];
        ((float4*)sw2)[tid] = ((const float4*)wz2)[tid];   // 1024 floats
        if (tid < 64) { sw3[tid] = wz3[tid]; sb1[tid] = b1[tid]; }
        else if (tid < 80)  sb2[tid - 64] = b2[tid - 64];
        else if (tid < 84)  sb3[tid - 80] = b3[tid - 80];
    }
    __syncthreads();

    const int lane = tid & 63;
    const int wid  = __builtin_amdgcn_readfirstlane(tid >> 6);
    const int rows_per_wave = groups_per_wave * 8;
    const int wave_row0 = blockIdx.x * (4 * rows_per_wave) + wid * rows_per_wave;

    float* my_h1 = sh1 + wid * (8 * H1_STRIDE);
    float* my_h2 = sh2 + wid * (8 * 16);

    const float bias1 = sb1[lane];
    const int i16 = lane & 15;
    const int grp = lane >> 4;
    float local_sum = 0.f;

    for (int g = 0; g < groups_per_wave; ++g) {
        const int row0 = wave_row0 + g * 8;
        const float* xr = x + (size_t)row0 * 256;   // wave-uniform base

        // ---- layer 1: h1[j] = relu(sum_k x[k]*w1[k][j] + b1[j]), j = lane ----
        float acc[8];
        #pragma unroll
        for (int r = 0; r < 8; ++r) acc[r] = bias1;

        for (int k = 0; k < 256; k += 4) {
            float4 xv[8];
            #pragma unroll
            for (int r = 0; r < 8; ++r)
                xv[r] = *(const float4*)(xr + r * 256 + k);   // uniform -> s_load
            const float w0 = sw1[(k + 0) * 64 + lane];
            const float w1v = sw1[(k + 1) * 64 + lane];
            const float w2v = sw1[(k + 2) * 64 + lane];
            const float w3v = sw1[(k + 3) * 64 + lane];
            #pragma unroll
            for (int r = 0; r < 8; ++r) {
                acc[r] = fmaf(xv[r].x, w0, acc[r]);
                acc[r] = fmaf(xv[r].y, w1v, acc[r]);
                acc[r] = fmaf(xv[r].z, w2v, acc[r]);
                acc[r] = fmaf(xv[r].w, w3v, acc[r]);
            }
        }
        #pragma unroll
        for (int r = 0; r < 8; ++r)
            my_h1[r * H1_STRIDE + lane] = fmaxf(acc[r], 0.f);
        __syncthreads();

        // ---- layer 2: 16 outputs x 8 rows over 64 lanes; lane = i16 + 16*grp ----
        #pragma unroll
        for (int rr = 0; rr < 2; ++rr) {
            const int r = grp + rr * 4;
            const float4* h1r4 = (const float4*)(my_h1 + r * H1_STRIDE);
            float a2 = sb2[i16];
            #pragma unroll
            for (int j4 = 0; j4 < 16; ++j4) {
                const float4 h = h1r4[j4];
                a2 = fmaf(h.x, sw2[(j4 * 4 + 0) * 16 + i16], a2);
                a2 = fmaf(h.y, sw2[(j4 * 4 + 1) * 16 + i16], a2);
                a2 = fmaf(h.z, sw2[(j4 * 4 + 2) * 16 + i16], a2);
                a2 = fmaf(h.w, sw2[(j4 * 4 + 3) * 16 + i16], a2);
            }
            my_h2[r * 16 + i16] = tanhf(a2);
        }
        __syncthreads();

        // ---- layer 3 + exp: 32 lanes (8 rows x 4 outputs) ----
        if (lane < 32) {
            const int c = lane & 3;
            const int r = lane >> 2;
            const float* h2r = my_h2 + r * 16;
            float a3 = sb3[c];
            #pragma unroll
            for (int i = 0; i < 16; ++i)
                a3 = fmaf(h2r[i], sw3[i * 4 + c], a3);
            const float e = expf(a3);            // h3 bounded ~|8| -> no overflow
            Eout[(size_t)row0 * 4 + lane] = e;   // (row0+r)*4+c == row0*4+lane
            local_sum += e;
        }
        __syncthreads();
    }

    // ---- block reduction of exp-sum (deterministic) ----
    #pragma unroll
    for (int off = 32; off > 0; off >>= 1)
        local_sum += __shfl_down(local_sum, off, 64);
    __syncthreads();
    if (lane == 0) smem[wid] = local_sum;   // sw1 no longer needed
    __syncthreads();
    if (tid == 0)
        block_sums[blockIdx.x] = (smem[0] + smem[1]) + (smem[2] + smem[3]);
}

__global__ __launch_bounds__(256) void reduce_kernel(
    const float* __restrict__ block_sums, float* __restrict__ s_inv)
{
    __shared__ float red[256];
    float s = 0.f;
    for (int i = threadIdx.x; i < NB1; i += 256) s += block_sums[i];
    red[threadIdx.x] = s;
    __syncthreads();
    #pragma unroll
    for (int o = 128; o > 0; o >>= 1) {
        if (threadIdx.x < o) red[threadIdx.x] += red[threadIdx.x + o];
        __syncthreads();
    }
    if (threadIdx.x == 0) s_inv[0] = 1.0f / red[0];
}

__global__ __launch_bounds__(256) void scale_kernel(
    float* __restrict__ out, const float* __restrict__ s_inv)
{
    const float inv = s_inv[0];
    const int idx = blockIdx.x * 256 + threadIdx.x;
    float4* o4 = (float4*)out;
    float4 v = o4[idx];
    v.x *= inv; v.y *= inv; v.z *= inv; v.w *= inv;
    o4[idx] = v;
}

extern "C" void kernel_launch(void* const* d_in, const int* in_sizes, int n_in,
                              void* d_out, int out_size, void* d_ws, size_t ws_size,
                              hipStream_t stream) {
    (void)n_in; (void)ws_size;
    const float* x   = (const float*)d_in[0];
    const float* wz1 = (const float*)d_in[1];
    const float* b1  = (const float*)d_in[2];
    const float* wz2 = (const float*)d_in[3];
    const float* b2  = (const float*)d_in[4];
    const float* wz3 = (const float*)d_in[5];
    const float* b3  = (const float*)d_in[6];
    float* out = (float*)d_out;

    float* wsf = (float*)d_ws;
    float* s_inv = wsf;              // 1 float
    float* block_sums = wsf + 1;     // NB1 floats

    const int B = in_sizes[0] / 256;              // 262144
    const int groups_per_wave = B / (NB1 * 4 * 8);  // 16

    hipFuncSetAttribute((const void*)fused_mlp_kernel,
                        hipFuncAttributeMaxDynamicSharedMemorySize, SMEM_BYTES);

    fused_mlp_kernel<<<NB1, TPB, SMEM_BYTES, stream>>>(
        x, wz1, b1, wz2, b2, wz3, b3, out, block_sums, groups_per_wave);
    reduce_kernel<<<1, 256, 0, stream>>>(block_sums, s_inv);

    const int n4 = out_size / 4;                  // 262144 float4
    scale_kernel<<<n4 / 256, 256, 0, stream>>>(out, s_inv);
}

// Round 2
// 325.392 us; speedup vs baseline: 2.4017x; 2.4017x over previous
//
#include <hip/hip_runtime.h>

// B = 262144 rows, 256 -> 64 (relu) -> 16 (tanh) -> 4 -> global softmax.
#define GRID 256      // 1 block per CU
#define TPB  512      // 8 waves
#define TILE_ROWS 32  // rows per LDS tile

// ---- dynamic LDS layout (float offsets) ----
#define OFF_W1   0                      // [256][64]      16384
#define OFF_W2T  16384                  // [16][68] padded 1088
#define OFF_W3   (OFF_W2T + 16*68)      // 17472: [16][4]   64
#define OFF_B1   (OFF_W3 + 64)          // 17536            64
#define OFF_B2   (OFF_B1 + 64)          // 17600            16
#define OFF_B3   (OFF_B2 + 16)          // 17616             4
#define OFF_X    (OFF_B3 + 4)           // 17620: 2 x [32][256] = 16384
#define OFF_PART (OFF_X + 2*TILE_ROWS*256)   // 34004: [32][64] = 2048
#define OFF_H1   (OFF_PART + TILE_ROWS*64)   // 36052: [32][68] = 2176
#define OFF_H2   (OFF_H1 + TILE_ROWS*68)     // 38228: [32][20] = 640
#define SMEM_FLOATS (OFF_H2 + TILE_ROWS*20)  // 38868
#define SMEM_BYTES (SMEM_FLOATS * 4)         // 155472 B <= 160 KiB

extern __shared__ float smem[];

__device__ __forceinline__ void gload_lds16(const float* g, float* l) {
    __builtin_amdgcn_global_load_lds(
        (const __attribute__((address_space(1))) void*)g,
        (__attribute__((address_space(3))) void*)l, 16, 0, 0);
}

// stage TILE_ROWS*256 floats (32 KB): wave wid stages a contiguous 4 KB chunk.
__device__ __forceinline__ void stage_tile(const float* xg, float* xb,
                                           int wid, int lane) {
    const float* g = xg + wid * 1024 + lane * 4;   // per-lane global addr
    float* l = xb + wid * 1024;                    // wave-uniform LDS base
    #pragma unroll
    for (int i = 0; i < 4; ++i)
        gload_lds16(g + i * 256, l + i * 256);     // HW adds lane*16
}

__global__ __launch_bounds__(TPB, 2) void fused_mlp_kernel(
    const float* __restrict__ x,
    const float* __restrict__ wz1, const float* __restrict__ b1,
    const float* __restrict__ wz2, const float* __restrict__ b2,
    const float* __restrict__ wz3, const float* __restrict__ b3,
    float* __restrict__ Eout, float* __restrict__ block_sums,
    int ntiles)
{
    float* sw1  = smem + OFF_W1;
    float* sw2t = smem + OFF_W2T;
    float* sw3  = smem + OFF_W3;
    float* sb1  = smem + OFF_B1;
    float* sb2  = smem + OFF_B2;
    float* sb3  = smem + OFF_B3;
    float* xbufs= smem + OFF_X;
    float* part = smem + OFF_PART;
    float* h1   = smem + OFF_H1;
    float* h2   = smem + OFF_H2;

    const int tid  = threadIdx.x;
    const int lane = tid & 63;
    const int wid  = __builtin_amdgcn_readfirstlane(tid >> 6);
    const int block_row0 = blockIdx.x * (ntiles * TILE_ROWS);

    // ---- prologue: kick off tile 0 x-load, then stage weights ----
    stage_tile(x + (size_t)block_row0 * 256, xbufs, wid, lane);
    {
        const float4* s1 = (const float4*)wz1;
        float4* d1 = (float4*)sw1;
        #pragma unroll
        for (int i = 0; i < 8; ++i) d1[tid + i * TPB] = s1[tid + i * TPB];
        for (int i = tid; i < 1024; i += TPB) {     // w2 transposed [16][68]
            const int k = i >> 4, c = i & 15;
            sw2t[c * 68 + k] = wz2[i];
        }
        if (tid < 64)      { sw3[tid] = wz3[tid]; sb1[tid] = b1[tid]; }
        else if (tid < 80)   sb2[tid - 64] = b2[tid - 64];
        else if (tid < 84)   sb3[tid - 80] = b3[tid - 80];
    }
    asm volatile("s_waitcnt vmcnt(0)" ::: "memory");
    __syncthreads();

    const int khalf = wid & 1;       // which 128-k half this wave computes
    const int rgrp  = wid >> 1;      // which 8-row group (0..3)
    const float bias1 = sb1[lane];
    float local_sum = 0.f;

    for (int t = 0; t < ntiles; ++t) {
        const int row0 = block_row0 + t * TILE_ROWS;
        if (t + 1 < ntiles)
            stage_tile(x + (size_t)(row0 + TILE_ROWS) * 256,
                       xbufs + ((t + 1) & 1) * (TILE_ROWS * 256), wid, lane);

        // ---- layer 1 (half-K per wave): 8 rows x 64 cols ----
        const float* xb = xbufs + (t & 1) * (TILE_ROWS * 256);
        const float* xk = xb + rgrp * 8 * 256 + khalf * 128;
        const float* w1p = sw1 + khalf * 128 * 64 + lane;

        float acc[8];
        #pragma unroll
        for (int r = 0; r < 8; ++r) acc[r] = khalf ? 0.f : bias1;

        #pragma unroll 4
        for (int q = 0; q < 32; ++q) {
            const int k = q * 4;
            const float w0 = w1p[(k + 0) * 64];
            const float w1v = w1p[(k + 1) * 64];
            const float w2v = w1p[(k + 2) * 64];
            const float w3v = w1p[(k + 3) * 64];
            #pragma unroll
            for (int r = 0; r < 8; ++r) {
                const float4 xv = *(const float4*)(xk + r * 256 + k);
                acc[r] = fmaf(xv.w, w3v, fmaf(xv.z, w2v,
                         fmaf(xv.y, w1v, fmaf(xv.x, w0, acc[r]))));
            }
        }

        if (khalf) {
            #pragma unroll
            for (int r = 0; r < 8; ++r)
                part[(rgrp * 8 + r) * 64 + lane] = acc[r];
        }
        __syncthreads();
        if (!khalf) {
            #pragma unroll
            for (int r = 0; r < 8; ++r) {
                const int row = rgrp * 8 + r;
                h1[row * 68 + lane] =
                    fmaxf(acc[r] + part[row * 64 + lane], 0.f);
            }
        }
        __syncthreads();

        // ---- layer 2: 32 rows x 16 cols = 512 tasks (one per thread) ----
        {
            const int row = tid >> 4, c = tid & 15;
            const float4* hp = (const float4*)(h1 + row * 68);
            const float4* wp = (const float4*)(sw2t + c * 68);
            float a2 = sb2[c];
            #pragma unroll
            for (int j = 0; j < 16; ++j) {
                const float4 h = hp[j], w = wp[j];
                a2 = fmaf(h.w, w.w, fmaf(h.z, w.z,
                     fmaf(h.y, w.y, fmaf(h.x, w.x, a2))));
            }
            h2[row * 20 + c] = tanhf(a2);
        }
        __syncthreads();

        // ---- layer 3 + exp: 32 rows x 4 cols = 128 tasks (waves 0,1) ----
        if (tid < 128) {
            const int row = tid >> 2, c = tid & 3;
            const float4* hp = (const float4*)(h2 + row * 20);
            float a3 = sb3[c];
            #pragma unroll
            for (int i4 = 0; i4 < 4; ++i4) {
                const float4 h = hp[i4];
                a3 = fmaf(h.x, sw3[(i4 * 4 + 0) * 4 + c], a3);
                a3 = fmaf(h.y, sw3[(i4 * 4 + 1) * 4 + c], a3);
                a3 = fmaf(h.z, sw3[(i4 * 4 + 2) * 4 + c], a3);
                a3 = fmaf(h.w, sw3[(i4 * 4 + 3) * 4 + c], a3);
            }
            const float e = expf(a3);        // h3 bounded, no overflow
            Eout[(size_t)row0 * 4 + tid] = e;
            local_sum += e;
        }
        // next tile's x must be resident; also separates LDS reuse hazards
        asm volatile("s_waitcnt vmcnt(0)" ::: "memory");
        __syncthreads();
    }

    // ---- block exp-sum reduction (deterministic) ----
    #pragma unroll
    for (int off = 32; off > 0; off >>= 1)
        local_sum += __shfl_down(local_sum, off, 64);
    if (lane == 0) part[wid] = local_sum;
    __syncthreads();
    if (tid == 0) {
        float s = 0.f;
        #pragma unroll
        for (int i = 0; i < TPB / 64; ++i) s += part[i];
        block_sums[blockIdx.x] = s;
    }
}

__global__ __launch_bounds__(256) void reduce_kernel(
    const float* __restrict__ block_sums, float* __restrict__ s_inv)
{
    __shared__ float red[256];
    float s = 0.f;
    for (int i = threadIdx.x; i < GRID; i += 256) s += block_sums[i];
    red[threadIdx.x] = s;
    __syncthreads();
    #pragma unroll
    for (int o = 128; o > 0; o >>= 1) {
        if (threadIdx.x < o) red[threadIdx.x] += red[threadIdx.x + o];
        __syncthreads();
    }
    if (threadIdx.x == 0) s_inv[0] = 1.0f / red[0];
}

__global__ __launch_bounds__(256) void scale_kernel(
    float* __restrict__ out, const float* __restrict__ s_inv)
{
    const float inv = s_inv[0];
    const int idx = blockIdx.x * 256 + threadIdx.x;
    float4* o4 = (float4*)out;
    float4 v = o4[idx];
    v.x *= inv; v.y *= inv; v.z *= inv; v.w *= inv;
    o4[idx] = v;
}

extern "C" void kernel_launch(void* const* d_in, const int* in_sizes, int n_in,
                              void* d_out, int out_size, void* d_ws, size_t ws_size,
                              hipStream_t stream) {
    (void)n_in; (void)ws_size;
    const float* x   = (const float*)d_in[0];
    const float* wz1 = (const float*)d_in[1];
    const float* b1  = (const float*)d_in[2];
    const float* wz2 = (const float*)d_in[3];
    const float* b2  = (const float*)d_in[4];
    const float* wz3 = (const float*)d_in[5];
    const float* b3  = (const float*)d_in[6];
    float* out = (float*)d_out;

    float* wsf = (float*)d_ws;
    float* s_inv = wsf;              // 1 float
    float* block_sums = wsf + 1;     // GRID floats

    const int B = in_sizes[0] / 256;               // 262144
    const int ntiles = B / (GRID * TILE_ROWS);     // 32

    hipFuncSetAttribute((const void*)fused_mlp_kernel,
                        hipFuncAttributeMaxDynamicSharedMemorySize, SMEM_BYTES);

    fused_mlp_kernel<<<GRID, TPB, SMEM_BYTES, stream>>>(
        x, wz1, b1, wz2, b2, wz3, b3, out, block_sums, ntiles);
    reduce_kernel<<<1, 256, 0, stream>>>(block_sums, s_inv);

    const int n4 = out_size / 4;
    scale_kernel<<<n4 / 256, 256, 0, stream>>>(out, s_inv);
}

// Round 3
// 62.600 us; speedup vs baseline: 12.4839x; 5.1979x over previous
//
#include <hip/hip_runtime.h>

// B = 262144 rows, 256 -> 64 (relu) -> 16 (tanh) -> 4 -> global softmax.
// Layer 1 & 2 on MFMA f16 with 2-way split operands (3-term products),
// power-of-2 scaled so split residuals stay f16-normal.

typedef _Float16 half8 __attribute__((ext_vector_type(8)));
typedef _Float16 half4 __attribute__((ext_vector_type(4)));
typedef float f32x4 __attribute__((ext_vector_type(4)));

#define GRID 256
#define TPB  512
#define TROWS 64

#define XS  264   // f16 stride for x rows (256 + 8 pad)
#define WS  264   // w1T stride
#define H1S 72    // h1 [row][j] stride (64 + 8)
#define W2S 72    // w2T stride

#define SCALE_IN 256.0f          // 2^8
#define SCALE_W  2048.0f         // 2^11
#define INV_SC   (1.0f/524288.0f)  // 2^-19

// ---- LDS byte offsets ----
#define OFF_XH  0
#define OFF_XL  (OFF_XH + TROWS*XS*2)      // 33792
#define OFF_W1H (OFF_XL + TROWS*XS*2)      // 67584
#define OFF_W1L (OFF_W1H + 64*WS*2)        // 101376
#define OFF_H1H (OFF_W1L + 64*WS*2)        // 135168
#define OFF_H1L (OFF_H1H + TROWS*H1S*2)    // 144384
#define OFF_W2H (OFF_H1L + TROWS*H1S*2)    // 153600
#define OFF_W2L (OFF_W2H + 16*W2S*2)       // 155904
#define OFF_SUM (OFF_W2L + 16*W2S*2)       // 158208
#define SMEM_BYTES (OFF_SUM + 64*4)        // 158464 <= 163840

extern __shared__ char smem_raw[];

#define MFMA16(a,b,c) __builtin_amdgcn_mfma_f32_16x16x32_f16((a),(b),(c),0,0,0)

__device__ __forceinline__ void lds_barrier() {
    asm volatile("s_waitcnt lgkmcnt(0)\ns_barrier" ::: "memory");
}

__global__ __launch_bounds__(TPB, 2) void fused_mlp(
    const float* __restrict__ x,
    const float* __restrict__ wz1, const float* __restrict__ b1,
    const float* __restrict__ wz2, const float* __restrict__ b2,
    const float* __restrict__ wz3, const float* __restrict__ b3,
    float* __restrict__ Eout, float* __restrict__ block_sums,
    int ntiles)
{
    _Float16* xh  = (_Float16*)(smem_raw + OFF_XH);
    _Float16* xl  = (_Float16*)(smem_raw + OFF_XL);
    _Float16* w1h = (_Float16*)(smem_raw + OFF_W1H);
    _Float16* w1l = (_Float16*)(smem_raw + OFF_W1L);
    _Float16* h1h = (_Float16*)(smem_raw + OFF_H1H);
    _Float16* h1l = (_Float16*)(smem_raw + OFF_H1L);
    _Float16* w2h = (_Float16*)(smem_raw + OFF_W2H);
    _Float16* w2l = (_Float16*)(smem_raw + OFF_W2L);
    float* sums   = (float*)(smem_raw + OFF_SUM);

    const int tid  = threadIdx.x;
    const int lane = tid & 63;
    const int wid  = __builtin_amdgcn_readfirstlane(tid >> 6);
    const int l15  = lane & 15;
    const int g8   = (lane >> 4) * 8;

    const size_t blk_row0 = (size_t)blockIdx.x * ntiles * TROWS;

    // ---- prologue: issue x tile-0 loads first (HBM latency overlap) ----
    float4 xv[8];
    {
        const float4* xg = (const float4*)(x + blk_row0 * 256);
        #pragma unroll
        for (int c = 0; c < 8; ++c) xv[c] = xg[c * TPB + tid];
    }

    // ---- stage w1T as scaled f16 hi/lo (once) ----
    {
        const float4* wg = (const float4*)wz1;   // 4096 float4
        #pragma unroll
        for (int c = 0; c < 8; ++c) {
            const int q = c * TPB + tid;         // 0..4095
            const float4 v = wg[q];
            const int k = q >> 4, n0 = (q & 15) * 4;
            const float vv[4] = {v.x, v.y, v.z, v.w};
            #pragma unroll
            for (int i = 0; i < 4; ++i) {
                const float s = vv[i] * SCALE_W;
                const _Float16 h = (_Float16)s;
                w1h[(n0 + i) * WS + k] = h;
                w1l[(n0 + i) * WS + k] = (_Float16)(s - (float)h);
            }
        }
        if (tid < 256) {                         // w2T: 256 float4
            const float4 v = ((const float4*)wz2)[tid];
            const int k = tid >> 2, c0 = (tid & 3) * 4;
            const float vv[4] = {v.x, v.y, v.z, v.w};
            #pragma unroll
            for (int i = 0; i < 4; ++i) {
                const float s = vv[i] * SCALE_W;
                const _Float16 h = (_Float16)s;
                w2h[(c0 + i) * W2S + k] = h;
                w2l[(c0 + i) * W2S + k] = (_Float16)(s - (float)h);
            }
        }
    }

    // ---- per-lane constants ----
    const int rt  = wid >> 1;                 // rowtile 0..3 (layer 1)
    const int ntp = wid & 1;                  // col-pair 0..1
    const int col0 = (2 * ntp) * 16 + l15;
    const int col1 = (2 * ntp + 1) * 16 + l15;
    const float b1v0 = b1[col0], b1v1 = b1[col1];
    float b2v[4], w3v[4][4];
    #pragma unroll
    for (int i = 0; i < 4; ++i) {
        const int c2 = (lane >> 4) * 4 + i;
        b2v[i] = b2[c2];
        #pragma unroll
        for (int c3 = 0; c3 < 4; ++c3) w3v[i][c3] = wz3[c2 * 4 + c3];
    }
    const float b3v[4] = {b3[0], b3[1], b3[2], b3[3]};

    lds_barrier();   // weights staged

    // ---- persistent register fragments ----
    half8 Bh[8][2];                           // w1 hi B-frags
    #pragma unroll
    for (int kt = 0; kt < 8; ++kt) {
        Bh[kt][0] = *(const half8*)(w1h + col0 * WS + kt * 32 + g8);
        Bh[kt][1] = *(const half8*)(w1h + col1 * WS + kt * 32 + g8);
    }
    half8 A2h[2], A2l[2];                     // w2T A-frags (layer 2)
    #pragma unroll
    for (int kt = 0; kt < 2; ++kt) {
        A2h[kt] = *(const half8*)(w2h + l15 * W2S + kt * 32 + g8);
        A2l[kt] = *(const half8*)(w2l + l15 * W2S + kt * 32 + g8);
    }

    float local_sum = 0.f;

    for (int t = 0; t < ntiles; ++t) {
        // ---- convert regs -> LDS f16 hi/lo (row = c*8+wid, k = lane*4) ----
        #pragma unroll
        for (int c = 0; c < 8; ++c) {
            const float vv[4] = {xv[c].x, xv[c].y, xv[c].z, xv[c].w};
            half4 hh, hl;
            #pragma unroll
            for (int i = 0; i < 4; ++i) {
                const float s = vv[i] * SCALE_IN;
                const _Float16 h = (_Float16)s;
                hh[i] = h;
                hl[i] = (_Float16)(s - (float)h);
            }
            const int row = c * 8 + wid;
            *(half4*)(xh + row * XS + lane * 4) = hh;
            *(half4*)(xl + row * XS + lane * 4) = hl;
        }
        // ---- issue next-tile global loads (stay in flight across barrier) ----
        if (t + 1 < ntiles) {
            const float4* xg2 =
                (const float4*)(x + (blk_row0 + (size_t)(t + 1) * TROWS) * 256);
            #pragma unroll
            for (int c = 0; c < 8; ++c) xv[c] = xg2[c * TPB + tid];
        }
        lds_barrier();   // B1: x(t) visible

        // ---- layer 1: 3-term split MFMA, rows rt*16..+15, cols col-pair ----
        f32x4 acc0 = {0.f, 0.f, 0.f, 0.f}, acc1 = {0.f, 0.f, 0.f, 0.f};
        {
            const _Float16* xh_p = xh + (rt * 16 + l15) * XS;
            const _Float16* xl_p = xl + (rt * 16 + l15) * XS;
            const _Float16* wl_p0 = w1l + col0 * WS;
            const _Float16* wl_p1 = w1l + col1 * WS;
            #pragma unroll
            for (int kt = 0; kt < 8; ++kt) {
                const int ko = kt * 32 + g8;
                const half8 ah  = *(const half8*)(xh_p + ko);
                const half8 al  = *(const half8*)(xl_p + ko);
                const half8 bl0 = *(const half8*)(wl_p0 + ko);
                const half8 bl1 = *(const half8*)(wl_p1 + ko);
                acc0 = MFMA16(ah, Bh[kt][0], acc0);
                acc1 = MFMA16(ah, Bh[kt][1], acc1);
                acc0 = MFMA16(al, Bh[kt][0], acc0);
                acc1 = MFMA16(al, Bh[kt][1], acc1);
                acc0 = MFMA16(ah, bl0, acc0);
                acc1 = MFMA16(ah, bl1, acc1);
            }
        }
        // ---- epilogue: scale+bias+relu -> h1 f16 hi/lo ----
        #pragma unroll
        for (int i = 0; i < 4; ++i) {
            const int r = rt * 16 + (lane >> 4) * 4 + i;
            const float h0 = fmaxf(fmaf(acc0[i], INV_SC, b1v0), 0.f);
            const float h1f = fmaxf(fmaf(acc1[i], INV_SC, b1v1), 0.f);
            const float s0 = h0 * SCALE_IN;
            const _Float16 h0h = (_Float16)s0;
            h1h[r * H1S + col0] = h0h;
            h1l[r * H1S + col0] = (_Float16)(s0 - (float)h0h);
            const float s1 = h1f * SCALE_IN;
            const _Float16 h1hh = (_Float16)s1;
            h1h[r * H1S + col1] = h1hh;
            h1l[r * H1S + col1] = (_Float16)(s1 - (float)h1hh);
        }
        lds_barrier();   // B2: h1 ready

        // ---- layer 2 (MFMA, h2^T = w2^T * h1^T) + layer 3 + exp: waves 0..3 ----
        if (wid < 4) {
            f32x4 a2 = {0.f, 0.f, 0.f, 0.f};
            const _Float16* hh_p = h1h + (wid * 16 + l15) * H1S;
            const _Float16* hl_p = h1l + (wid * 16 + l15) * H1S;
            #pragma unroll
            for (int kt = 0; kt < 2; ++kt) {
                const int ko = kt * 32 + g8;
                const half8 bh = *(const half8*)(hh_p + ko);
                const half8 bl = *(const half8*)(hl_p + ko);
                a2 = MFMA16(A2h[kt], bh, a2);
                a2 = MFMA16(A2l[kt], bh, a2);
                a2 = MFMA16(A2h[kt], bl, a2);
            }
            // lane holds h2pre for c2 = (lane>>4)*4+i, row = wid*16 + l15
            float p0 = 0.f, p1 = 0.f, p2 = 0.f, p3 = 0.f;
            #pragma unroll
            for (int i = 0; i < 4; ++i) {
                const float h2 = tanhf(fmaf(a2[i], INV_SC, b2v[i]));
                p0 = fmaf(h2, w3v[i][0], p0);
                p1 = fmaf(h2, w3v[i][1], p1);
                p2 = fmaf(h2, w3v[i][2], p2);
                p3 = fmaf(h2, w3v[i][3], p3);
            }
            p0 += __shfl_xor(p0, 16, 64); p0 += __shfl_xor(p0, 32, 64);
            p1 += __shfl_xor(p1, 16, 64); p1 += __shfl_xor(p1, 32, 64);
            p2 += __shfl_xor(p2, 16, 64); p2 += __shfl_xor(p2, 32, 64);
            p3 += __shfl_xor(p3, 16, 64); p3 += __shfl_xor(p3, 32, 64);
            if (lane < 16) {
                const float e0 = expf(p0 + b3v[0]);
                const float e1 = expf(p1 + b3v[1]);
                const float e2 = expf(p2 + b3v[2]);
                const float e3 = expf(p3 + b3v[3]);
                const size_t row = blk_row0 + (size_t)t * TROWS + wid * 16 + lane;
                float4 ev; ev.x = e0; ev.y = e1; ev.z = e2; ev.w = e3;
                *(float4*)(Eout + row * 4) = ev;
                local_sum += (e0 + e1) + (e2 + e3);
            }
        }
    }

    // ---- block exp-sum reduction (deterministic) ----
    #pragma unroll
    for (int off = 32; off > 0; off >>= 1)
        local_sum += __shfl_down(local_sum, off, 64);
    if (lane == 0) sums[wid] = local_sum;
    lds_barrier();
    if (tid == 0) {
        float s = 0.f;
        #pragma unroll
        for (int w = 0; w < 8; ++w) s += sums[w];
        block_sums[blockIdx.x] = s;
    }
}

__global__ __launch_bounds__(256) void reduce_kernel(
    const float* __restrict__ block_sums, float* __restrict__ s_inv)
{
    __shared__ float red[256];
    float s = 0.f;
    for (int i = threadIdx.x; i < GRID; i += 256) s += block_sums[i];
    red[threadIdx.x] = s;
    __syncthreads();
    #pragma unroll
    for (int o = 128; o > 0; o >>= 1) {
        if (threadIdx.x < o) red[threadIdx.x] += red[threadIdx.x + o];
        __syncthreads();
    }
    if (threadIdx.x == 0) s_inv[0] = 1.0f / red[0];
}

__global__ __launch_bounds__(256) void scale_kernel(
    float* __restrict__ out, const float* __restrict__ s_inv)
{
    const float inv = s_inv[0];
    const int idx = blockIdx.x * 256 + threadIdx.x;
    float4* o4 = (float4*)out;
    float4 v = o4[idx];
    v.x *= inv; v.y *= inv; v.z *= inv; v.w *= inv;
    o4[idx] = v;
}

extern "C" void kernel_launch(void* const* d_in, const int* in_sizes, int n_in,
                              void* d_out, int out_size, void* d_ws, size_t ws_size,
                              hipStream_t stream) {
    (void)n_in; (void)ws_size;
    const float* x   = (const float*)d_in[0];
    const float* wz1 = (const float*)d_in[1];
    const float* b1  = (const float*)d_in[2];
    const float* wz2 = (const float*)d_in[3];
    const float* b2  = (const float*)d_in[4];
    const float* wz3 = (const float*)d_in[5];
    const float* b3  = (const float*)d_in[6];
    float* out = (float*)d_out;

    float* wsf = (float*)d_ws;
    float* s_inv = wsf;              // 1 float
    float* block_sums = wsf + 1;     // GRID floats

    const int B = in_sizes[0] / 256;             // 262144
    const int ntiles = B / (GRID * TROWS);       // 16

    hipFuncSetAttribute((const void*)fused_mlp,
                        hipFuncAttributeMaxDynamicSharedMemorySize, SMEM_BYTES);

    fused_mlp<<<GRID, TPB, SMEM_BYTES, stream>>>(
        x, wz1, b1, wz2, b2, wz3, b3, out, block_sums, ntiles);
    reduce_kernel<<<1, 256, 0, stream>>>(block_sums, s_inv);

    const int n4 = out_size / 4;
    scale_kernel<<<n4 / 256, 256, 0, stream>>>(out, s_inv);
}